// Round 13
// baseline (146.514 us; speedup 1.0000x reference)
//
#include <hip/hip_runtime.h>
#include <hip/hip_bf16.h>
#include <cstdint>

#define NEG_BIG (-1.0e9f)

typedef __attribute__((ext_vector_type(8))) short short8_t;
typedef __attribute__((ext_vector_type(4))) float f32x4;

typedef __attribute__((address_space(1))) const unsigned int gu32_t;
typedef __attribute__((address_space(3))) unsigned int lu32_t;

__device__ __forceinline__ short f2bf(float x) {
  union { float f; unsigned u; } v; v.f = x;
  unsigned r = v.u + 0x7fffu + ((v.u >> 16) & 1u);
  return (short)(r >> 16);
}
__device__ __forceinline__ float sigmoidf_(float x) { return 1.0f / (1.0f + __expf(-x)); }

// barrier with LDS-visibility only: vmcnt stays un-drained (loads stay in flight)
__device__ __forceinline__ void lds_barrier() {
  asm volatile("s_waitcnt lgkmcnt(0)\n\ts_barrier" ::: "memory");
}
// plain barrier (no waitcnt) for k_attn streaming loop (vmcnt handled explicitly)
__device__ __forceinline__ void block_barrier() {
  asm volatile("" ::: "memory");
  __builtin_amdgcn_s_barrier();
  asm volatile("" ::: "memory");
}

// ---------------- K0: pack A1 = [emb[prev] | h0] as bf16, rows of 1536 ----------------
__global__ void k_pack_a1(const int* __restrict__ prev, const float* __restrict__ emb,
                          const float* __restrict__ h0, short* __restrict__ A1) {
  int t = blockIdx.x * 256 + threadIdx.x;
  if (t >= 128 * 1536) return;
  int b = t / 1536, k = t - b * 1536;
  float v = (k < 512) ? emb[(size_t)prev[b] * 512 + k] : h0[b * 1024 + (k - 512)];
  A1[t] = f2bf(v);
}

// ------- M-tiled bf16-MFMA GEMM, 2-phase reg-staged pipeline, optional split-K -------
template <int MB, int WN, int EPI>
__launch_bounds__(256, 2)
__global__ void k_gemm(const short* __restrict__ A, int lda,
                       const float* __restrict__ Wa, int ldwa, int Ka,
                       const float* __restrict__ Wb, int ldwb, int Ktot,
                       const float* __restrict__ bias0, const float* __restrict__ bias1,
                       float* __restrict__ outF, short* __restrict__ outB, int ldo,
                       int kstride, size_t pstride) {
  constexpr int BN = WN * 16;
  constexpr int MREP = (MB == 128) ? 2 * WN : 1;
  constexpr int AU = MB / 32;
  constexpr int WLOADS = (BN * 64) / 1024;
  __shared__ __align__(16) short lA[2][MB * 64];
  __shared__ __align__(16) short lW[2][BN * 64];
  const int kc = blockIdx.z;
  A += (size_t)kc * kstride;
  Wa += (size_t)kc * kstride;
  if (outF) outF += (size_t)kc * pstride;
  const int tid = threadIdx.x;
  const int wid = tid >> 6, l = tid & 63, l15 = l & 15, khalf = l >> 4;
  const int nblk = blockIdx.x;
  const int mrow0 = blockIdx.y * MB;
  const int m_wave = (WN == 1) ? wid * (MB / 4) : 0;
  const int nb_local = (WN == 4) ? wid * 16 : 0;

  const int arow = (MB == 128) ? (tid >> 1) : (tid >> 2);
  const int apart = (MB == 128) ? (tid & 1) : (tid & 3);
  const int abase = apart * (AU * 16);
  const int aswz = (arow & 7) << 4;
  const short* Arow = A + (size_t)(mrow0 + arow) * lda + apart * (AU * 8);

  int wn_[WLOADS], wkq_[WLOADS];
#pragma unroll
  for (int j = 0; j < WLOADS; ++j) {
    int idx = j * 1024 + tid * 4;
    wn_[j] = idx >> 6;
    wkq_[j] = idx & 63;
  }

  f32x4 acc[MREP];
#pragma unroll
  for (int r = 0; r < MREP; ++r) acc[r] = (f32x4){0.f, 0.f, 0.f, 0.f};

  short8_t aR[AU];
  float4 wR[WLOADS];

  auto stage_regs = [&](int k0) {
#pragma unroll
    for (int q = 0; q < AU; ++q) aR[q] = *(const short8_t*)(Arow + k0 + q * 8);
#pragma unroll
    for (int j = 0; j < WLOADS; ++j) {
      int kg = k0 + wkq_[j];
      const float* p = (kg < Ka) ? (Wa + (size_t)(nblk * BN + wn_[j]) * ldwa + kg)
                                 : (Wb + (size_t)(nblk * BN + wn_[j]) * ldwb + (kg - Ka));
      wR[j] = *(const float4*)p;
    }
  };
  auto write_lds = [&](int buf) {
    char* drow = (char*)lA[buf] + arow * 128;
#pragma unroll
    for (int q = 0; q < AU; ++q)
      *(short8_t*)(drow + ((abase + q * 16) ^ aswz)) = aR[q];
#pragma unroll
    for (int j = 0; j < WLOADS; ++j) {
      short4 h4;
      h4.x = f2bf(wR[j].x); h4.y = f2bf(wR[j].y); h4.z = f2bf(wR[j].z); h4.w = f2bf(wR[j].w);
      *(short4*)((char*)lW[buf] + wn_[j] * 128 + ((wkq_[j] * 2) ^ ((wn_[j] & 7) << 4))) = h4;
    }
  };
  auto compute = [&](int buf) {
#pragma unroll
    for (int ks = 0; ks < 2; ++ks) {
      const int ubyte = ks * 64 + khalf * 16;
      const int nrow = nb_local + l15;
      short8_t bfrag = *(const short8_t*)((char*)lW[buf] + nrow * 128 + (ubyte ^ ((nrow & 7) << 4)));
#pragma unroll
      for (int r = 0; r < MREP; ++r) {
        const int mrow = m_wave + r * 16 + l15;
        short8_t afrag = *(const short8_t*)((char*)lA[buf] + mrow * 128 + (ubyte ^ ((mrow & 7) << 4)));
        acc[r] = __builtin_amdgcn_mfma_f32_16x16x32_bf16(afrag, bfrag, acc[r], 0, 0, 0);
      }
    }
  };

  const int NT = Ktot >> 6;
  stage_regs(0);
  write_lds(0);
  for (int t = 0; t < NT; ++t) {
    const int cur = t & 1;
    if (t + 1 < NT) stage_regs((t + 1) << 6);  // loads in flight across barrier
    lds_barrier();                             // LDS visibility only; vmcnt free
    compute(cur);
    if (t + 1 < NT) write_lds(cur ^ 1);
  }

  const int n = nblk * BN + nb_local + l15;
  float bias = 0.f;
  if (bias0) bias = bias0[n];
  if (bias1) bias += bias1[n];
#pragma unroll
  for (int r = 0; r < MREP; ++r) {
    int mb = mrow0 + m_wave + r * 16 + khalf * 4;
#pragma unroll
    for (int e = 0; e < 4; ++e) {
      float v = acc[r][e] + bias;
      if (EPI == 1) {
        outB[(size_t)(mb + e) * ldo + n] = f2bf(tanhf(v));
      } else {
        outF[(size_t)(mb + e) * ldo + n] = v;
      }
    }
  }
}

// ---------------- K2: LSTM elementwise ----------------
__global__ void k_lstm(const float* __restrict__ gates, const float* __restrict__ c0,
                       float* __restrict__ h1_out, float* __restrict__ c1_out,
                       short* __restrict__ A3) {
  int t = blockIdx.x * 256 + threadIdx.x;  // 131072
  int b = t >> 10, h = t & 1023;
  const float* g = gates + (size_t)b * 4096;
  float ig = sigmoidf_(g[h]);
  float fg = sigmoidf_(g[1024 + h]);
  float gg = tanhf(g[2048 + h]);
  float og = sigmoidf_(g[3072 + h]);
  float c1 = fg * c0[t] + ig * gg;
  float h1 = og * tanhf(c1);
  c1_out[t] = c1;
  h1_out[t] = h1;
  A3[(size_t)b * 2048 + 1024 + h] = f2bf(h1);  // second half of concat row
}

// ---------------- K3: flash attention, LDS-staged streaming (ctx read ONCE) -----------
// grid 512: b = bid>>2, chunk = bid&3 (128 rows). target = sum of 4 K-partials on load.
// Epilogue: block-level combine of the 4 wave partials -> part[b][chunk] (1 per block).
__launch_bounds__(256, 2)
__global__ void k_attn(const float* __restrict__ ctx, const float* __restrict__ tp,
                       const unsigned char* __restrict__ mask,
                       float* __restrict__ scores, float* __restrict__ part) {
  __shared__ __align__(16) float lds[2][8 * 1024];  // 2 x 32KB
  __shared__ float sml[8];
  const int b = blockIdx.x >> 2, chunk = blockIdx.x & 3;
  const int tid = threadIdx.x;
  const int wid = tid >> 6, l = tid & 63;
  float4 t4[4], w4[4];
#pragma unroll
  for (int j = 0; j < 4; ++j) {
    float4 a = {0.f, 0.f, 0.f, 0.f};
#pragma unroll
    for (int p = 0; p < 4; ++p) {
      const float4 v = *(const float4*)(tp + (size_t)p * 131072 + (size_t)b * 1024 + j * 256 + l * 4);
      a.x += v.x; a.y += v.y; a.z += v.z; a.w += v.w;
    }
    t4[j] = a;
    w4[j].x = 0.f; w4[j].y = 0.f; w4[j].z = 0.f; w4[j].w = 0.f;
  }
  float m = -INFINITY, lsum = 0.f;
  const int s0 = chunk * 128;
  const float* cb = ctx + ((size_t)b * 512 + s0) * 1024;
  const unsigned char* mk = mask + (size_t)b * 512 + s0;

  auto stage = [&](int buf, int tt) {
    const char* src = (const char*)(cb + (size_t)tt * 8192);
    char* dst = (char*)&lds[buf][0];
#pragma unroll
    for (int i = 0; i < 8; ++i) {
      const int off = i * 4096 + tid * 16;
      __builtin_amdgcn_global_load_lds((gu32_t*)(src + off), (lu32_t*)(dst + off), 16, 0, 0);
    }
  };

  stage(0, 0);
  int buf = 0;
  for (int t = 0; t < 16; ++t) {
    if (t < 15) {
      stage(buf ^ 1, t + 1);
      asm volatile("s_waitcnt vmcnt(8)" ::: "memory");  // tile t done; t+1 in flight
    } else {
      asm volatile("s_waitcnt vmcnt(0)" ::: "memory");
    }
    block_barrier();  // B1: tile t visible to all waves
#pragma unroll
    for (int rr = 0; rr < 2; ++rr) {
      const int r = wid * 2 + rr;
      const float* row = &lds[buf][r * 1024];
      float4 c0 = *(const float4*)(row + l * 4);
      float4 c1 = *(const float4*)(row + 256 + l * 4);
      float4 c2 = *(const float4*)(row + 512 + l * 4);
      float4 c3 = *(const float4*)(row + 768 + l * 4);
      float p = c0.x * t4[0].x + c0.y * t4[0].y + c0.z * t4[0].z + c0.w * t4[0].w +
                c1.x * t4[1].x + c1.y * t4[1].y + c1.z * t4[1].z + c1.w * t4[1].w +
                c2.x * t4[2].x + c2.y * t4[2].y + c2.z * t4[2].z + c2.w * t4[2].w +
                c3.x * t4[3].x + c3.y * t4[3].y + c3.z * t4[3].z + c3.w * t4[3].w;
#pragma unroll
      for (int off = 32; off > 0; off >>= 1) p += __shfl_xor(p, off);
      const int sg = t * 8 + r;
      if (mk[sg]) p = NEG_BIG;
      if (l == 0) scores[(size_t)b * 512 + s0 + sg] = p;
      float mn = fmaxf(m, p);
      float scale = __expf(m - mn);
      float e = __expf(p - mn);
      lsum = lsum * scale + e;
      w4[0].x = w4[0].x * scale + e * c0.x; w4[0].y = w4[0].y * scale + e * c0.y;
      w4[0].z = w4[0].z * scale + e * c0.z; w4[0].w = w4[0].w * scale + e * c0.w;
      w4[1].x = w4[1].x * scale + e * c1.x; w4[1].y = w4[1].y * scale + e * c1.y;
      w4[1].z = w4[1].z * scale + e * c1.z; w4[1].w = w4[1].w * scale + e * c1.w;
      w4[2].x = w4[2].x * scale + e * c2.x; w4[2].y = w4[2].y * scale + e * c2.y;
      w4[2].z = w4[2].z * scale + e * c2.z; w4[2].w = w4[2].w * scale + e * c2.w;
      w4[3].x = w4[3].x * scale + e * c3.x; w4[3].y = w4[3].y * scale + e * c3.y;
      w4[3].z = w4[3].z * scale + e * c3.z; w4[3].w = w4[3].w * scale + e * c3.w;
      m = mn;
    }
    block_barrier();  // B2: all waves done reading lds[buf] before overwrite
    buf ^= 1;
  }

  // ---- block-level combine: 4 wave partials -> 1 (vmcnt drained by last tile) ----
  float* cbuf = &lds[0][0];  // [4][1024]
#pragma unroll
  for (int j = 0; j < 4; ++j) *(float4*)(cbuf + wid * 1024 + j * 256 + l * 4) = w4[j];
  if (l == 0) { sml[wid] = m; sml[4 + wid] = lsum; }
  __syncthreads();
  const float M = fmaxf(fmaxf(sml[0], sml[1]), fmaxf(sml[2], sml[3]));
  const float sc0 = __expf(sml[0] - M), sc1 = __expf(sml[1] - M);
  const float sc2 = __expf(sml[2] - M), sc3 = __expf(sml[3] - M);
  const float L = sml[4] * sc0 + sml[5] * sc1 + sml[6] * sc2 + sml[7] * sc3;
  const float4 v0 = *(const float4*)(cbuf + 0 * 1024 + tid * 4);
  const float4 v1 = *(const float4*)(cbuf + 1 * 1024 + tid * 4);
  const float4 v2 = *(const float4*)(cbuf + 2 * 1024 + tid * 4);
  const float4 v3 = *(const float4*)(cbuf + 3 * 1024 + tid * 4);
  float4 o;
  o.x = v0.x * sc0 + v1.x * sc1 + v2.x * sc2 + v3.x * sc3;
  o.y = v0.y * sc0 + v1.y * sc1 + v2.y * sc2 + v3.y * sc3;
  o.z = v0.z * sc0 + v1.z * sc1 + v2.z * sc2 + v3.z * sc3;
  o.w = v0.w * sc0 + v1.w * sc1 + v2.w * sc2 + v3.w * sc3;
  float* pp = part + ((size_t)b * 4 + chunk) * 1028;
  *(float4*)(pp + tid * 4) = o;
  if (tid == 0) { pp[1024] = M; pp[1025] = L; }
}

// ====== K4: W_out GEMM, split-K x8, A-staging fuses the softmax combine ======
// kc<4: A cols from the 4 attn partials, combined with per-row coef (no weighted buffer).
// kc>=4: A cols = bf16 h1 half of A3. Out: wp[kc][128][1024] f32 partials.
__launch_bounds__(256, 2)
__global__ void k_wgemm(const short* __restrict__ A3, const float* __restrict__ part,
                        const float* __restrict__ W_out, float* __restrict__ wp) {
  __shared__ __align__(16) short lA[2][128 * 64];
  __shared__ __align__(16) short lW[2][16 * 64];
  const int kc = blockIdx.z, nblk = blockIdx.x;
  const int tid = threadIdx.x;
  const int wid = tid >> 6, l = tid & 63, l15 = l & 15, khalf = l >> 4;
  const int arow = tid >> 1, apart = tid & 1;  // 2 thr/row, 32 cols each
  const int aswz = (arow & 7) << 4;
  const bool wpath = (kc < 4);

  const int colbase = kc * 256 + apart * 32;
  const short* ArowB = A3 + (size_t)arow * 2048 + colbase;
  const float* ps = part + (size_t)arow * 4 * 1028;
  const float* pr0 = ps + colbase;
  const float* pr1 = ps + 1028 + colbase;
  const float* pr2 = ps + 2056 + colbase;
  const float* pr3 = ps + 3084 + colbase;
  float coef0 = 0.f, coef1 = 0.f, coef2 = 0.f, coef3 = 0.f;
  if (wpath) {
    float m0 = ps[1024], l0 = ps[1025], m1 = ps[1028 + 1024], l1 = ps[1028 + 1025];
    float m2 = ps[2056 + 1024], l2 = ps[2056 + 1025], m3 = ps[3084 + 1024], l3 = ps[3084 + 1025];
    float M = fmaxf(fmaxf(m0, m1), fmaxf(m2, m3));
    float s0 = __expf(m0 - M), s1 = __expf(m1 - M), s2 = __expf(m2 - M), s3 = __expf(m3 - M);
    float inv = 1.0f / (l0 * s0 + l1 * s1 + l2 * s2 + l3 * s3);
    coef0 = s0 * inv; coef1 = s1 * inv; coef2 = s2 * inv; coef3 = s3 * inv;
  }

  const int wn = (tid * 4) >> 6, wkq = (tid * 4) & 63;
  const float* wrow = W_out + (size_t)(nblk * 16 + wn) * 2048 + kc * 256;

  f32x4 acc[2];
  acc[0] = (f32x4){0.f, 0.f, 0.f, 0.f};
  acc[1] = (f32x4){0.f, 0.f, 0.f, 0.f};
  float4 aC[8];
  short8_t aB[4];
  float4 wR;

  auto stage_regs = [&](int k0) {
    if (wpath) {
#pragma unroll
      for (int q = 0; q < 8; ++q) {
        const float4 v0 = *(const float4*)(pr0 + k0 + q * 4);
        const float4 v1 = *(const float4*)(pr1 + k0 + q * 4);
        const float4 v2 = *(const float4*)(pr2 + k0 + q * 4);
        const float4 v3 = *(const float4*)(pr3 + k0 + q * 4);
        aC[q].x = coef0 * v0.x + coef1 * v1.x + coef2 * v2.x + coef3 * v3.x;
        aC[q].y = coef0 * v0.y + coef1 * v1.y + coef2 * v2.y + coef3 * v3.y;
        aC[q].z = coef0 * v0.z + coef1 * v1.z + coef2 * v2.z + coef3 * v3.z;
        aC[q].w = coef0 * v0.w + coef1 * v1.w + coef2 * v2.w + coef3 * v3.w;
      }
    } else {
#pragma unroll
      for (int q = 0; q < 4; ++q) aB[q] = *(const short8_t*)(ArowB + k0 + q * 8);
    }
    wR = *(const float4*)(wrow + k0 + wkq);
  };
  auto write_lds = [&](int buf) {
    char* drow = (char*)lA[buf] + arow * 128;
    if (wpath) {
#pragma unroll
      for (int q2 = 0; q2 < 4; ++q2) {
        short8_t s;
        s[0] = f2bf(aC[2 * q2].x); s[1] = f2bf(aC[2 * q2].y);
        s[2] = f2bf(aC[2 * q2].z); s[3] = f2bf(aC[2 * q2].w);
        s[4] = f2bf(aC[2 * q2 + 1].x); s[5] = f2bf(aC[2 * q2 + 1].y);
        s[6] = f2bf(aC[2 * q2 + 1].z); s[7] = f2bf(aC[2 * q2 + 1].w);
        *(short8_t*)(drow + ((apart * 64 + q2 * 16) ^ aswz)) = s;
      }
    } else {
#pragma unroll
      for (int q = 0; q < 4; ++q)
        *(short8_t*)(drow + ((apart * 64 + q * 16) ^ aswz)) = aB[q];
    }
    short4 h4;
    h4.x = f2bf(wR.x); h4.y = f2bf(wR.y); h4.z = f2bf(wR.z); h4.w = f2bf(wR.w);
    *(short4*)((char*)lW[buf] + wn * 128 + ((wkq * 2) ^ ((wn & 7) << 4))) = h4;
  };
  auto compute = [&](int buf) {
#pragma unroll
    for (int ks = 0; ks < 2; ++ks) {
      const int ubyte = ks * 64 + khalf * 16;
      short8_t bfrag = *(const short8_t*)((char*)lW[buf] + l15 * 128 + (ubyte ^ ((l15 & 7) << 4)));
#pragma unroll
      for (int r = 0; r < 2; ++r) {
        const int mrow = wid * 32 + r * 16 + l15;
        short8_t afrag = *(const short8_t*)((char*)lA[buf] + mrow * 128 + (ubyte ^ ((mrow & 7) << 4)));
        acc[r] = __builtin_amdgcn_mfma_f32_16x16x32_bf16(afrag, bfrag, acc[r], 0, 0, 0);
      }
    }
  };

  stage_regs(0);
  write_lds(0);
  for (int t = 0; t < 4; ++t) {
    const int cur = t & 1;
    if (t + 1 < 4) stage_regs((t + 1) << 6);
    lds_barrier();
    compute(cur);
    if (t + 1 < 4) write_lds(cur ^ 1);
  }

  const int n = nblk * 16 + l15;
  float* out = wp + (size_t)kc * 131072;
#pragma unroll
  for (int r = 0; r < 2; ++r) {
    int mb = wid * 32 + r * 16 + khalf * 4;
#pragma unroll
    for (int e = 0; e < 4; ++e)
      out[(size_t)(mb + e) * 1024 + n] = acc[r][e];
  }
}

// ====== K5: htilde = bf16(tanh(sum of 8 wp)) + alpha from scores/part scalars ======
__global__ void k_fin2(const float* __restrict__ wp, const float* __restrict__ part,
                       const float* __restrict__ scores, short* __restrict__ ht,
                       float* __restrict__ alpha) {
  int t = blockIdx.x * 256 + threadIdx.x;  // 131072
  float s = 0.f;
#pragma unroll
  for (int p = 0; p < 8; ++p) s += wp[(size_t)p * 131072 + t];
  ht[t] = f2bf(tanhf(s));
  if (t < 65536) {
    int b = t >> 9, si = t & 511;
    const float* ps = part + (size_t)b * 4 * 1028;
    float m0 = ps[1024], l0 = ps[1025], m1 = ps[1028 + 1024], l1 = ps[1028 + 1025];
    float m2 = ps[2056 + 1024], l2 = ps[2056 + 1025], m3 = ps[3084 + 1024], l3 = ps[3084 + 1025];
    float M = fmaxf(fmaxf(m0, m1), fmaxf(m2, m3));
    float L = l0 * __expf(m0 - M) + l1 * __expf(m1 - M) + l2 * __expf(m2 - M) +
              l3 * __expf(m3 - M);
    alpha[t] = __expf(scores[(size_t)b * 512 + si] - M) / L;
  }
}

extern "C" void kernel_launch(void* const* d_in, const int* in_sizes, int n_in,
                              void* d_out, int out_size, void* d_ws, size_t ws_size,
                              hipStream_t stream) {
  const int* prev = (const int*)d_in[0];
  const float* h0 = (const float*)d_in[1];
  const float* c0 = (const float*)d_in[2];
  const float* ctx = (const float*)d_in[3];
  const unsigned char* mask = (const unsigned char*)d_in[4];
  const float* emb = (const float*)d_in[5];
  const float* W_ih = (const float*)d_in[6];
  const float* W_hh = (const float*)d_in[7];
  const float* b_ih = (const float*)d_in[8];
  const float* b_hh = (const float*)d_in[9];
  const float* W_in = (const float*)d_in[10];
  const float* W_out = (const float*)d_in[11];
  const float* W_dec = (const float*)d_in[12];
  const float* b_dec = (const float*)d_in[13];

  float* out_h1 = (float*)d_out;            // 128*1024
  float* out_c1 = out_h1 + 128 * 1024;      // 128*1024
  float* out_alpha = out_c1 + 128 * 1024;   // 128*512
  float* out_logit = out_alpha + 128 * 512; // 128*32000

  char* ws = (char*)d_ws;
  short* A3 = (short*)(ws + 0x000000);      // 128x2048 bf16 [unused | h1] (512KB)
  float* scores = (float*)(ws + 0x100000);  // 128x512 f32 (256KB)
  float* tp = (float*)(ws + 0x200000);      // 4 x 128x1024 f32 target partials (2MB)
  float* part = (float*)(ws + 0x400000);    // 128x4x1028 f32 (2.1MB)
  float* wp = (float*)(ws + 0x700000);      // 8 x 128x1024 f32 wout partials (4MB)
  float* gates = (float*)(ws + 0xB00000);   // 128x4096 f32 (2MB)
  short* A1 = (short*)(ws + 0xD00000);      // 128x1536 bf16 (384KB)
  short* htilde = (short*)(ws + 0xE00000);  // 128x1024 bf16 (256KB)

  // 1) pack gather+h0 operand
  k_pack_a1<<<768, 256, 0, stream>>>(prev, emb, h0, A1);
  // 2) gates = [emb|h0] @ [W_ih|W_hh]^T + b_ih + b_hh (N=4096, K=1536, 256 blocks)
  k_gemm<128, 1, 0><<<dim3(256, 1, 1), 256, 0, stream>>>(
      A1, 1536, W_ih, 512, 512, W_hh, 1024, 1536, b_ih, b_hh, gates, nullptr, 4096, 0, 0);
  // 3) LSTM cell -> h_1, c_1 (+ bf16 h1 into A3 second half)
  k_lstm<<<512, 256, 0, stream>>>(gates, c0, out_h1, out_c1, A3);
  // 4) target partials = h1 @ W_in^T, split-K x4 (256 blocks, 64KB W/block)
  k_gemm<128, 1, 0><<<dim3(64, 1, 4), 256, 0, stream>>>(
      A3 + 1024, 2048, W_in, 1024, 1 << 30, W_in, 1024, 256, nullptr, nullptr, tp, nullptr,
      1024, 256, (size_t)131072);
  // 5) flash attention over ctx (read once); block-combined partials + scores
  k_attn<<<512, 256, 0, stream>>>(ctx, tp, mask, scores, part);
  // 6) wout partials, split-K x8 (512 blocks); weighted-half A fused from attn partials
  k_wgemm<<<dim3(64, 1, 8), 256, 0, stream>>>(A3, part, W_out, wp);
  // 7) htilde = tanh(sum wp) + alpha
  k_fin2<<<512, 256, 0, stream>>>(wp, part, scores, htilde, out_alpha);
  // 8) logit = h_tilde @ W_dec^T + b_dec (N=32000, K=1024, 500 blocks)
  k_gemm<128, 4, 0><<<dim3(500, 1, 1), 256, 0, stream>>>(
      htilde, 1024, W_dec, 1024, 1024, W_dec, 1024, 1024, b_dec, nullptr, out_logit, nullptr,
      32000, 0, 0);
}

// Round 14
// 134.099 us; speedup vs baseline: 1.0926x; 1.0926x over previous
//
#include <hip/hip_runtime.h>
#include <hip/hip_bf16.h>
#include <cstdint>

#define NEG_BIG (-1.0e9f)

typedef __attribute__((ext_vector_type(8))) short short8_t;
typedef __attribute__((ext_vector_type(4))) float f32x4;

typedef __attribute__((address_space(1))) const unsigned int gu32_t;
typedef __attribute__((address_space(3))) unsigned int lu32_t;

__device__ __forceinline__ short f2bf(float x) {
  union { float f; unsigned u; } v; v.f = x;
  unsigned r = v.u + 0x7fffu + ((v.u >> 16) & 1u);
  return (short)(r >> 16);
}
__device__ __forceinline__ float sigmoidf_(float x) { return 1.0f / (1.0f + __expf(-x)); }

// barrier with LDS-visibility only: vmcnt stays un-drained (loads stay in flight)
__device__ __forceinline__ void lds_barrier() {
  asm volatile("s_waitcnt lgkmcnt(0)\n\ts_barrier" ::: "memory");
}
// plain barrier (no waitcnt) for k_attn streaming loop (vmcnt handled explicitly)
__device__ __forceinline__ void block_barrier() {
  asm volatile("" ::: "memory");
  __builtin_amdgcn_s_barrier();
  asm volatile("" ::: "memory");
}

// ---------------- K0: pack A1 = [emb[prev] | h0] as bf16, rows of 1536 ----------------
__global__ void k_pack_a1(const int* __restrict__ prev, const float* __restrict__ emb,
                          const float* __restrict__ h0, short* __restrict__ A1) {
  int t = blockIdx.x * 256 + threadIdx.x;
  if (t >= 128 * 1536) return;
  int b = t / 1536, k = t - b * 1536;
  float v = (k < 512) ? emb[(size_t)prev[b] * 512 + k] : h0[b * 1024 + (k - 512)];
  A1[t] = f2bf(v);
}

// ------- M-tiled bf16-MFMA GEMM, 2-phase reg-staged pipeline, optional split-K -------
// C[128][N] (or partial) = A(bf16)[128][K] @ W(f32)[N][K]^T
// blockIdx.z = K-chunk: offsets A,Wa by z*kstride cols and outF by z*pstride elems.
template <int MB, int WN, int EPI>
__launch_bounds__(256, 2)
__global__ void k_gemm(const short* __restrict__ A, int lda,
                       const float* __restrict__ Wa, int ldwa, int Ka,
                       const float* __restrict__ Wb, int ldwb, int Ktot,
                       const float* __restrict__ bias0, const float* __restrict__ bias1,
                       float* __restrict__ outF, short* __restrict__ outB, int ldo,
                       int kstride, size_t pstride) {
  constexpr int BN = WN * 16;
  constexpr int MREP = (MB == 128) ? 2 * WN : 1;
  constexpr int AU = MB / 32;
  constexpr int WLOADS = (BN * 64) / 1024;
  __shared__ __align__(16) short lA[2][MB * 64];
  __shared__ __align__(16) short lW[2][BN * 64];
  const int kc = blockIdx.z;
  A += (size_t)kc * kstride;
  Wa += (size_t)kc * kstride;
  if (outF) outF += (size_t)kc * pstride;
  const int tid = threadIdx.x;
  const int wid = tid >> 6, l = tid & 63, l15 = l & 15, khalf = l >> 4;
  const int nblk = blockIdx.x;
  const int mrow0 = blockIdx.y * MB;
  const int m_wave = (WN == 1) ? wid * (MB / 4) : 0;
  const int nb_local = (WN == 4) ? wid * 16 : 0;

  const int arow = (MB == 128) ? (tid >> 1) : (tid >> 2);
  const int apart = (MB == 128) ? (tid & 1) : (tid & 3);
  const int abase = apart * (AU * 16);
  const int aswz = (arow & 7) << 4;
  const short* Arow = A + (size_t)(mrow0 + arow) * lda + apart * (AU * 8);

  int wn_[WLOADS], wkq_[WLOADS];
#pragma unroll
  for (int j = 0; j < WLOADS; ++j) {
    int idx = j * 1024 + tid * 4;
    wn_[j] = idx >> 6;
    wkq_[j] = idx & 63;
  }

  f32x4 acc[MREP];
#pragma unroll
  for (int r = 0; r < MREP; ++r) acc[r] = (f32x4){0.f, 0.f, 0.f, 0.f};

  short8_t aR[AU];
  float4 wR[WLOADS];

  auto stage_regs = [&](int k0) {
#pragma unroll
    for (int q = 0; q < AU; ++q) aR[q] = *(const short8_t*)(Arow + k0 + q * 8);
#pragma unroll
    for (int j = 0; j < WLOADS; ++j) {
      int kg = k0 + wkq_[j];
      const float* p = (kg < Ka) ? (Wa + (size_t)(nblk * BN + wn_[j]) * ldwa + kg)
                                 : (Wb + (size_t)(nblk * BN + wn_[j]) * ldwb + (kg - Ka));
      wR[j] = *(const float4*)p;
    }
  };
  auto write_lds = [&](int buf) {
    char* drow = (char*)lA[buf] + arow * 128;
#pragma unroll
    for (int q = 0; q < AU; ++q)
      *(short8_t*)(drow + ((abase + q * 16) ^ aswz)) = aR[q];
#pragma unroll
    for (int j = 0; j < WLOADS; ++j) {
      short4 h4;
      h4.x = f2bf(wR[j].x); h4.y = f2bf(wR[j].y); h4.z = f2bf(wR[j].z); h4.w = f2bf(wR[j].w);
      *(short4*)((char*)lW[buf] + wn_[j] * 128 + ((wkq_[j] * 2) ^ ((wn_[j] & 7) << 4))) = h4;
    }
  };
  auto compute = [&](int buf) {
#pragma unroll
    for (int ks = 0; ks < 2; ++ks) {
      const int ubyte = ks * 64 + khalf * 16;
      const int nrow = nb_local + l15;
      short8_t bfrag = *(const short8_t*)((char*)lW[buf] + nrow * 128 + (ubyte ^ ((nrow & 7) << 4)));
#pragma unroll
      for (int r = 0; r < MREP; ++r) {
        const int mrow = m_wave + r * 16 + l15;
        short8_t afrag = *(const short8_t*)((char*)lA[buf] + mrow * 128 + (ubyte ^ ((mrow & 7) << 4)));
        acc[r] = __builtin_amdgcn_mfma_f32_16x16x32_bf16(afrag, bfrag, acc[r], 0, 0, 0);
      }
    }
  };

  const int NT = Ktot >> 6;
  stage_regs(0);
  write_lds(0);
  for (int t = 0; t < NT; ++t) {
    const int cur = t & 1;
    if (t + 1 < NT) stage_regs((t + 1) << 6);  // loads in flight across barrier
    lds_barrier();                             // LDS visibility only; vmcnt free
    compute(cur);
    if (t + 1 < NT) write_lds(cur ^ 1);
  }

  const int n = nblk * BN + nb_local + l15;
  float bias = 0.f;
  if (bias0) bias = bias0[n];
  if (bias1) bias += bias1[n];
#pragma unroll
  for (int r = 0; r < MREP; ++r) {
    int mb = mrow0 + m_wave + r * 16 + khalf * 4;
#pragma unroll
    for (int e = 0; e < 4; ++e) {
      float v = acc[r][e] + bias;
      if (EPI == 1) {
        outB[(size_t)(mb + e) * ldo + n] = f2bf(tanhf(v));
      } else {
        outF[(size_t)(mb + e) * ldo + n] = v;
      }
    }
  }
}

// ---------------- K2: LSTM elementwise ----------------
__global__ void k_lstm(const float* __restrict__ gates, const float* __restrict__ c0,
                       float* __restrict__ h1_out, float* __restrict__ c1_out,
                       short* __restrict__ A3) {
  int t = blockIdx.x * 256 + threadIdx.x;  // 131072
  int b = t >> 10, h = t & 1023;
  const float* g = gates + (size_t)b * 4096;
  float ig = sigmoidf_(g[h]);
  float fg = sigmoidf_(g[1024 + h]);
  float gg = tanhf(g[2048 + h]);
  float og = sigmoidf_(g[3072 + h]);
  float c1 = fg * c0[t] + ig * gg;
  float h1 = og * tanhf(c1);
  c1_out[t] = c1;
  h1_out[t] = h1;
  A3[(size_t)b * 2048 + 1024 + h] = f2bf(h1);  // second half of concat row
}

// ---------------- K4: flash attention, LDS-staged streaming (ctx read ONCE) -----------
// grid 512: b = bid>>2, chunk = bid&3 (128 rows). target read as sum of 4 K-partials.
__launch_bounds__(256, 2)
__global__ void k_attn(const float* __restrict__ ctx, const float* __restrict__ tp,
                       const unsigned char* __restrict__ mask,
                       float* __restrict__ scores, float* __restrict__ part) {
  __shared__ __align__(16) float lds[2][8 * 1024];  // 2 x 32KB
  const int b = blockIdx.x >> 2, chunk = blockIdx.x & 3;
  const int tid = threadIdx.x;
  const int wid = tid >> 6, l = tid & 63;
  float4 t4[4], w4[4];
#pragma unroll
  for (int j = 0; j < 4; ++j) {
    float4 a = {0.f, 0.f, 0.f, 0.f};
#pragma unroll
    for (int p = 0; p < 4; ++p) {
      const float4 v = *(const float4*)(tp + (size_t)p * 131072 + (size_t)b * 1024 + j * 256 + l * 4);
      a.x += v.x; a.y += v.y; a.z += v.z; a.w += v.w;
    }
    t4[j] = a;
    w4[j].x = 0.f; w4[j].y = 0.f; w4[j].z = 0.f; w4[j].w = 0.f;
  }
  float m = -INFINITY, lsum = 0.f;
  const int s0 = chunk * 128;
  const float* cb = ctx + ((size_t)b * 512 + s0) * 1024;
  const unsigned char* mk = mask + (size_t)b * 512 + s0;

  auto stage = [&](int buf, int tt) {
    const char* src = (const char*)(cb + (size_t)tt * 8192);
    char* dst = (char*)&lds[buf][0];
#pragma unroll
    for (int i = 0; i < 8; ++i) {
      const int off = i * 4096 + tid * 16;
      __builtin_amdgcn_global_load_lds((gu32_t*)(src + off), (lu32_t*)(dst + off), 16, 0, 0);
    }
  };

  stage(0, 0);
  int buf = 0;
  for (int t = 0; t < 16; ++t) {
    if (t < 15) {
      stage(buf ^ 1, t + 1);
      asm volatile("s_waitcnt vmcnt(8)" ::: "memory");  // tile t done; t+1 in flight
    } else {
      asm volatile("s_waitcnt vmcnt(0)" ::: "memory");
    }
    block_barrier();  // B1: tile t visible to all waves
#pragma unroll
    for (int rr = 0; rr < 2; ++rr) {
      const int r = wid * 2 + rr;
      const float* row = &lds[buf][r * 1024];
      float4 c0 = *(const float4*)(row + l * 4);
      float4 c1 = *(const float4*)(row + 256 + l * 4);
      float4 c2 = *(const float4*)(row + 512 + l * 4);
      float4 c3 = *(const float4*)(row + 768 + l * 4);
      float p = c0.x * t4[0].x + c0.y * t4[0].y + c0.z * t4[0].z + c0.w * t4[0].w +
                c1.x * t4[1].x + c1.y * t4[1].y + c1.z * t4[1].z + c1.w * t4[1].w +
                c2.x * t4[2].x + c2.y * t4[2].y + c2.z * t4[2].z + c2.w * t4[2].w +
                c3.x * t4[3].x + c3.y * t4[3].y + c3.z * t4[3].z + c3.w * t4[3].w;
#pragma unroll
      for (int off = 32; off > 0; off >>= 1) p += __shfl_xor(p, off);
      const int sg = t * 8 + r;
      if (mk[sg]) p = NEG_BIG;
      if (l == 0) scores[(size_t)b * 512 + s0 + sg] = p;
      float mn = fmaxf(m, p);
      float scale = __expf(m - mn);
      float e = __expf(p - mn);
      lsum = lsum * scale + e;
      w4[0].x = w4[0].x * scale + e * c0.x; w4[0].y = w4[0].y * scale + e * c0.y;
      w4[0].z = w4[0].z * scale + e * c0.z; w4[0].w = w4[0].w * scale + e * c0.w;
      w4[1].x = w4[1].x * scale + e * c1.x; w4[1].y = w4[1].y * scale + e * c1.y;
      w4[1].z = w4[1].z * scale + e * c1.z; w4[1].w = w4[1].w * scale + e * c1.w;
      w4[2].x = w4[2].x * scale + e * c2.x; w4[2].y = w4[2].y * scale + e * c2.y;
      w4[2].z = w4[2].z * scale + e * c2.z; w4[2].w = w4[2].w * scale + e * c2.w;
      w4[3].x = w4[3].x * scale + e * c3.x; w4[3].y = w4[3].y * scale + e * c3.y;
      w4[3].z = w4[3].z * scale + e * c3.z; w4[3].w = w4[3].w * scale + e * c3.w;
      m = mn;
    }
    block_barrier();  // B2: all waves done reading lds[buf] before overwrite
    buf ^= 1;
  }
  float* pp = part + ((size_t)b * 16 + (chunk * 4 + wid)) * 1028;
#pragma unroll
  for (int j = 0; j < 4; ++j) *(float4*)(pp + j * 256 + l * 4) = w4[j];
  if (l == 0) { pp[1024] = m; pp[1025] = lsum; }
}

// ------- K5: finish = exact alpha (from partial m/l) + combine partials -------
__launch_bounds__(256, 4)
__global__ void k_finish(const float* __restrict__ scores, const float* __restrict__ part,
                         float* __restrict__ alpha, short* __restrict__ A3) {
  __shared__ float sm[16], sl[16];
  int b = blockIdx.x, t = threadIdx.x;
  if (t < 16) {
    sm[t] = part[((size_t)b * 16 + t) * 1028 + 1024];
    sl[t] = part[((size_t)b * 16 + t) * 1028 + 1025];
  }
  __syncthreads();
  float M = -INFINITY;
#pragma unroll
  for (int i = 0; i < 16; ++i) M = fmaxf(M, sm[i]);
  float scl[16];
  float L = 0.f;
#pragma unroll
  for (int i = 0; i < 16; ++i) {
    scl[i] = __expf(sm[i] - M);
    L += sl[i] * scl[i];
  }
  float inv = 1.0f / L;
  float s0 = scores[(size_t)b * 512 + t];
  float s1 = scores[(size_t)b * 512 + 256 + t];
  alpha[(size_t)b * 512 + t] = __expf(s0 - M) * inv;
  alpha[(size_t)b * 512 + 256 + t] = __expf(s1 - M) * inv;
  float ax = 0.f, ay = 0.f, az = 0.f, aw = 0.f;
#pragma unroll
  for (int i = 0; i < 16; ++i) {
    const float4 w = *(const float4*)(part + ((size_t)b * 16 + i) * 1028 + t * 4);
    ax += scl[i] * w.x; ay += scl[i] * w.y; az += scl[i] * w.z; aw += scl[i] * w.w;
  }
  short4 o4;
  o4.x = f2bf(ax * inv); o4.y = f2bf(ay * inv); o4.z = f2bf(az * inv); o4.w = f2bf(aw * inv);
  *(short4*)(A3 + (size_t)b * 2048 + t * 4) = o4;
}

// ------- K6: htilde = bf16(tanh(sum of 8 wout K-partials)) -------
__global__ void k_htilde(const float* __restrict__ wp, short* __restrict__ ht) {
  int t = blockIdx.x * 256 + threadIdx.x;  // 131072
  float s = 0.f;
#pragma unroll
  for (int p = 0; p < 8; ++p) s += wp[(size_t)p * 131072 + t];
  ht[t] = f2bf(tanhf(s));
}

extern "C" void kernel_launch(void* const* d_in, const int* in_sizes, int n_in,
                              void* d_out, int out_size, void* d_ws, size_t ws_size,
                              hipStream_t stream) {
  const int* prev = (const int*)d_in[0];
  const float* h0 = (const float*)d_in[1];
  const float* c0 = (const float*)d_in[2];
  const float* ctx = (const float*)d_in[3];
  const unsigned char* mask = (const unsigned char*)d_in[4];
  const float* emb = (const float*)d_in[5];
  const float* W_ih = (const float*)d_in[6];
  const float* W_hh = (const float*)d_in[7];
  const float* b_ih = (const float*)d_in[8];
  const float* b_hh = (const float*)d_in[9];
  const float* W_in = (const float*)d_in[10];
  const float* W_out = (const float*)d_in[11];
  const float* W_dec = (const float*)d_in[12];
  const float* b_dec = (const float*)d_in[13];

  float* out_h1 = (float*)d_out;            // 128*1024
  float* out_c1 = out_h1 + 128 * 1024;      // 128*1024
  float* out_alpha = out_c1 + 128 * 1024;   // 128*512
  float* out_logit = out_alpha + 128 * 512; // 128*32000

  char* ws = (char*)d_ws;
  short* A3 = (short*)(ws + 0x000000);      // 128x2048 bf16 [weighted | h1] (512KB)
  float* scores = (float*)(ws + 0x100000);  // 128x512 f32 (256KB)
  float* tp = (float*)(ws + 0x200000);      // 4 x 128x1024 f32 target partials (2MB)
  float* part = (float*)(ws + 0x400000);    // 128x16x1028 f32 (8.42MB)
  float* wp = (float*)(ws + 0xD00000);      // 8 x 128x1024 f32 wout partials (4MB)
  float* gates = (float*)(ws + 0x1100000);  // 128x4096 f32 (2MB)
  short* A1 = (short*)(ws + 0x1300000);     // 128x1536 bf16 (384KB)
  short* htilde = (short*)(ws + 0x1400000); // 128x1024 bf16 (256KB)

  // 1) pack gather+h0 operand
  k_pack_a1<<<768, 256, 0, stream>>>(prev, emb, h0, A1);
  // 2) gates = [emb|h0] @ [W_ih|W_hh]^T + b_ih + b_hh (N=4096, K=1536, 256 blocks)
  k_gemm<128, 1, 0><<<dim3(256, 1, 1), 256, 0, stream>>>(
      A1, 1536, W_ih, 512, 512, W_hh, 1024, 1536, b_ih, b_hh, gates, nullptr, 4096, 0, 0);
  // 3) LSTM cell -> h_1, c_1 (+ bf16 h1 into A3 second half)
  k_lstm<<<512, 256, 0, stream>>>(gates, c0, out_h1, out_c1, A3);
  // 4) target partials = h1 @ W_in^T, split-K x4 (256 blocks, 64KB W/block)
  k_gemm<128, 1, 0><<<dim3(64, 1, 4), 256, 0, stream>>>(
      A3 + 1024, 2048, W_in, 1024, 1 << 30, W_in, 1024, 256, nullptr, nullptr, tp, nullptr,
      1024, 256, (size_t)131072);
  // 5) flash attention over ctx (read once); target = sum of 4 partials on load
  k_attn<<<512, 256, 0, stream>>>(ctx, tp, mask, scores, part);
  // 6) alpha + combine partials -> weighted (bf16 into A3 first half)
  k_finish<<<128, 256, 0, stream>>>(scores, part, out_alpha, A3);
  // 7) wout partials = [weighted|h1] @ W_out^T, split-K x8 (512 blocks, 64KB W/block)
  k_gemm<128, 1, 0><<<dim3(64, 1, 8), 256, 0, stream>>>(
      A3, 2048, W_out, 2048, 1 << 30, W_out, 2048, 256, nullptr, nullptr, wp, nullptr,
      1024, 256, (size_t)131072);
  // 8) htilde = tanh(sum of wout partials), bf16
  k_htilde<<<512, 256, 0, stream>>>(wp, htilde);
  // 9) logit = h_tilde @ W_dec^T + b_dec (N=32000, K=1024, 500 blocks)
  k_gemm<128, 4, 0><<<dim3(500, 1, 1), 256, 0, stream>>>(
      htilde, 1024, W_dec, 1024, 1024, W_dec, 1024, 1024, b_dec, nullptr, out_logit, nullptr,
      32000, 0, 0);
}